// Round 15
// baseline (2070.060 us; speedup 1.0000x reference)
//
#include <hip/hip_runtime.h>
#include <math.h>

#define N16 1600
#define M 32
#define XSZ 51200
#define BIS_IT 28
#define EPSF 1e-12f
#define NBLK 250
#define NPH 30
#define LDSF 17728  // mv: Ws 2x2592 + XsT 2x5184 + Red 2176

// Fused cooperative solve, 250 blocks. Round-13/14 failure root-caused: the
// round-8 MV decomposition needs 400 block-units (200 i-groups x 2 k-halves)
// but mv_phase only ran 200 (bx<200, ig=bx>>1 in 0..99) -> rows 800..1599 of
// every X iterate were NEVER WRITTEN (deterministic 0.3476 absmax in both
// rounds, both paths). FIX: each working block runs TWO i-groups serially
// (ig = (bx>>1) + 100*half). Summation order per output element is exactly
// the round-8 body -> numerics bit-identical. Coherence: plain stores +
// release/acquire __threadfence in the grid barrier (grid.sync semantics).
// Fallback: 30 sequential k_step launches (kernel-boundary coherence).

// ---------------- wave reductions -------------------------------------------
__device__ __forceinline__ float wred(float v) {
#pragma unroll
  for (int o = 32; o; o >>= 1) v += __shfl_xor(v, o, 64);
  return v;
}

// ---------------- grid barrier with release/acquire (250 blocks) ------------
// 16 arrival counters 4 KB apart; master at barr[16*1024]; gen at
// barr[17*1024]. Monotonic, never reset. 250 = 10*16 + 6*15.
__device__ __forceinline__ void grid_barrier(unsigned* barr, int s, int bx, int t) {
  __threadfence();   // RELEASE: flush this block's writes to coherence point
  __syncthreads();
  if (t == 0) {
    unsigned* gen = barr + 17 * 1024;
    const int lane = bx & 15;
    const unsigned quota = 15u + ((lane < 10) ? 1u : 0u);
    unsigned a = __hip_atomic_fetch_add(barr + lane * 1024, 1u, __ATOMIC_RELAXED,
                                        __HIP_MEMORY_SCOPE_AGENT);
    bool done = false;
    if (a + 1u == (unsigned)(s + 1) * quota) {
      unsigned m = __hip_atomic_fetch_add(barr + 16 * 1024, 1u, __ATOMIC_RELAXED,
                                          __HIP_MEMORY_SCOPE_AGENT);
      if (m + 1u == (unsigned)(s + 1) * 16u) {
        __hip_atomic_store(gen, (unsigned)(s + 1), __ATOMIC_RELAXED,
                           __HIP_MEMORY_SCOPE_AGENT);
        done = true;
      }
    }
    if (!done)
      while ((int)__hip_atomic_load(gen, __ATOMIC_RELAXED,
                                    __HIP_MEMORY_SCOPE_AGENT) <= s)
        __builtin_amdgcn_s_sleep(2);
  }
  __syncthreads();
  __threadfence();   // ACQUIRE: invalidate stale cached lines before reads
}

// ---------------- phase: resize (bx<168) ------------------------------------
__device__ void taps1d(int o, int* lo, int* hi, float* wsum, float w[8]) {
  int l = 4 * o - 2, h = 4 * o + 5;
  if (l < 0) l = 0;
  if (h > 159) h = 159;
  float c = 4.f * o + 1.5f, s = 0.f;
  for (int x = l; x <= h; ++x) {
    float ww = 1.f - fabsf((float)x - c) * 0.25f;
    w[x - l] = ww;
    s += ww;
  }
  *lo = l; *hi = h; *wsum = s;
}

__device__ void resize_phase(const float* __restrict__ in, float* __restrict__ rz,
                             int bx, int t) {
  int map = bx / 7;
  int o = (bx % 7) * 256 + t;
  if (o >= N16) return;
  int oy = o / 40, ox = o % 40;
  int ly, hy, lx, hx; float sy, sx; float wy[8], wx[8];
  taps1d(oy, &ly, &hy, &sy, wy);
  taps1d(ox, &lx, &hx, &sx, wx);
  const float* src = in + (size_t)map * 160 * 160;
  float acc = 0.f;
  for (int y = ly; y <= hy; ++y) {
    float a = 0.f;
    const float* row = src + y * 160;
    for (int x = lx; x <= hx; ++x) a += wx[x - lx] * row[x];
    acc += wy[y - ly] * a;
  }
  rz[map * N16 + o] = acc / (sy * sx);
}

// ---------------- phase: prep (bx<23) ---------------------------------------
__device__ void prep_phase(const float* __restrict__ rz, float* __restrict__ F,
                           int* __restrict__ flags, float* LDSu, int bx, int t) {
  int* sp = (int*)LDSu;
  int* sn = sp + 256;
  if (bx < 16) {
    int b = bx >> 1, c = bx & 1;
    const float* m = rz + (b * 3 + c) * N16;
    int cp = 0, cn = 0;
    for (int o = t; o < N16; o += 256) {
      float v = m[o];
      cp += (v > 0.f);
      cn += (v < 0.f);
    }
    sp[t] = cp; sn[t] = cn;
    __syncthreads();
    for (int s = 128; s > 0; s >>= 1) {
      if (t < s) { sp[t] += sp[t + s]; sn[t] += sn[t + s]; }
      __syncthreads();
    }
    if (t == 0) flags[bx] = (sp[0] == 0 || sn[0] == 0) ? 1 : 0;
  } else if (bx < 23) {
    int n = (bx - 16) * 256 + t;
    if (n < N16) {
      float x = rz[n], y = rz[N16 + n], z = rz[2 * N16 + n];
      float nrm = sqrtf(x * x + y * y + z * z);
      float s = 1.f / fmaxf(nrm, EPSF);
      F[n * 3 + 0] = x * s;
      F[n * 3 + 1] = y * s;
      F[n * 3 + 2] = z * s;
    }
  }
}

// ---------------- phase: degree + G4 + X0 init (bx<100) ---------------------
__device__ void degree_phase(const float* __restrict__ F, float* __restrict__ R,
                             float* __restrict__ G4f, float* __restrict__ X0,
                             float* LDSu, int bx, int t) {
  float* Fl = LDSu;          // 4800
  float* red = LDSu + 4800;  // 256
  for (int s = t; s < 4800; s += 256) Fl[s] = F[s];
  __syncthreads();
  int rl = t >> 4, jt = t & 15;
  int i = bx * 16 + rl;
  float fx = Fl[i * 3], fy = Fl[i * 3 + 1], fz = Fl[i * 3 + 2];
  float s = 0.f;
#pragma unroll 8
  for (int j = jt; j < N16; j += 16) {
    float w = fx * Fl[j * 3] + fy * Fl[j * 3 + 1] + fz * Fl[j * 3 + 2];
    if (w > 0.f) s += w;
  }
  red[t] = s;
  __syncthreads();
  for (int st = 8; st > 0; st >>= 1) {
    if (jt < st) red[t] += red[t + st];
    __syncthreads();
  }
  if (jt == 0) {
    float d = red[t];
    if (d < EPSF) d = 1.f;
    float r = rsqrtf(d);
    R[i] = r;
    G4f[i * 4 + 0] = r * fx;
    G4f[i * 4 + 1] = r * fy;
    G4f[i * 4 + 2] = r * fz;
    G4f[i * 4 + 3] = 0.f;
  }
  for (int e = t; e < 512; e += 256) {
    int n = bx * 16 + (e >> 5);
    int k = e & 31;
    unsigned u = ((unsigned)n * 2654435761u) ^ ((unsigned)k * 0x9E3779B9u);
    u = u * 1664525u + 1013904223u;
    u ^= u >> 16; u *= 2246822519u; u ^= u >> 13;
    X0[n * M + k] = ((float)(u >> 8) * (1.f / 8388608.f)) - 1.f;
  }
}

// ---------------- phase: MV (bx<200; TWO i-groups per block) ----------------
// Round-8 verified internals. Unit (ig,kh): ig = (bx>>1)+100*half covers
// 0..199; kh = bx&1. All 1600 rows written. Safety between halves: the
// post-Red __syncthreads orders all XsB/WsB reads of half h before half
// h+1's staging writes; Red region is disjoint from XsB/WsB.
__device__ void mv_phase(const float* __restrict__ F, const float4* __restrict__ G4,
                         const float* __restrict__ R, const float* __restrict__ Xin,
                         float* __restrict__ Xout, float* LDSu, int bx, int t) {
  if (bx >= 200) return;
  float* WsB  = LDSu;           // 2 x [8][324]
  float* XsB  = LDSu + 5184;    // 2 x [16][324]
  float* Red  = LDSu + 15552;   // 16 x 136
  const int kh = bx & 1;
  const int kbase = kh * 16;
  const int rg = t & 3, kg = (t >> 2) & 3, jg = t >> 4;
  const int sj = t >> 2, sq = t & 3;
  const int wil = t & 7, wjg = t >> 3;
  const float4* Xin4 = (const float4*)Xin;

  for (int half = 0; half < 2; ++half) {
    const int ig = (bx >> 1) + 100 * half;
    const int i0 = ig * 8;
    const float fx = F[(i0 + wil) * 3 + 0];
    const float fy = F[(i0 + wil) * 3 + 1];
    const float fz = F[(i0 + wil) * 3 + 2];

    float acc[2][4];
#pragma unroll
    for (int r = 0; r < 2; ++r)
#pragma unroll
      for (int kk = 0; kk < 4; ++kk) acc[r][kk] = 0.f;

    // prologue: stage chunk 0 (j = 0..319) into buffer 0
#pragma unroll
    for (int p = 0; p < 5; ++p) {
      float4 xs = Xin4[(size_t)(p * 64 + sj) * 8 + kh * 4 + sq];
      XsB[(sq * 4 + 0) * 324 + p * 64 + sj] = xs.x;
      XsB[(sq * 4 + 1) * 324 + p * 64 + sj] = xs.y;
      XsB[(sq * 4 + 2) * 324 + p * 64 + sj] = xs.z;
      XsB[(sq * 4 + 3) * 324 + p * 64 + sj] = xs.w;
    }
#pragma unroll
    for (int q = 0; q < 10; ++q) {
      float4 g = G4[wjg + 32 * q];
      WsB[wil * 324 + wjg + 32 * q] =
          fmaxf(fx * g.x + fy * g.y + fz * g.z, 0.f);
    }
    __syncthreads();

    for (int c = 0; c < 5; ++c) {
      const int cur = c & 1, nxt = cur ^ 1;
      float* Wc = WsB + cur * 2592;
      float* Xc = XsB + cur * 5184;
      float4 xsr[5];
      float4 gar[10];
      if (c < 4) {
        const int jb = (c + 1) * 320;
#pragma unroll
        for (int p = 0; p < 5; ++p)
          xsr[p] = Xin4[(size_t)(jb + p * 64 + sj) * 8 + kh * 4 + sq];
#pragma unroll
        for (int q = 0; q < 10; ++q) gar[q] = G4[jb + wjg + 32 * q];
      }
#pragma unroll
      for (int ss = 0; ss < 5; ++ss) {
        const int jq = ss * 64 + jg * 4;
        float4 wv[2], xv[4];
#pragma unroll
        for (int r = 0; r < 2; ++r)
          wv[r] = *(const float4*)&Wc[(rg * 2 + r) * 324 + jq];
#pragma unroll
        for (int kk = 0; kk < 4; ++kk)
          xv[kk] = *(const float4*)&Xc[(kg * 4 + kk) * 324 + jq];
#pragma unroll
        for (int r = 0; r < 2; ++r)
#pragma unroll
          for (int kk = 0; kk < 4; ++kk)
            acc[r][kk] += wv[r].x * xv[kk].x + wv[r].y * xv[kk].y +
                          wv[r].z * xv[kk].z + wv[r].w * xv[kk].w;
      }
      if (c < 4) {
        float* Wn = WsB + nxt * 2592;
        float* Xn = XsB + nxt * 5184;
#pragma unroll
        for (int p = 0; p < 5; ++p) {
          Xn[(sq * 4 + 0) * 324 + p * 64 + sj] = xsr[p].x;
          Xn[(sq * 4 + 1) * 324 + p * 64 + sj] = xsr[p].y;
          Xn[(sq * 4 + 2) * 324 + p * 64 + sj] = xsr[p].z;
          Xn[(sq * 4 + 3) * 324 + p * 64 + sj] = xsr[p].w;
        }
#pragma unroll
        for (int q = 0; q < 10; ++q)
          Wn[wil * 324 + wjg + 32 * q] =
              fmaxf(fx * gar[q].x + fy * gar[q].y + fz * gar[q].z, 0.f);
      }
      __syncthreads();
    }

#pragma unroll
    for (int r = 0; r < 2; ++r)
#pragma unroll
      for (int kk = 0; kk < 4; ++kk)
        Red[jg * 136 + (rg * 2 + r) * 16 + (kg * 4 + kk)] = acc[r][kk];
    __syncthreads();
    if (t < 128) {
      const int il = t >> 4, kl = t & 15;
      float sv = 0.f;
#pragma unroll
      for (int g = 0; g < 16; ++g) sv += Red[g * 136 + il * 16 + kl];
      const int gi = i0 + il, gk = kbase + kl;
      Xout[(size_t)gi * 32 + gk] =
          0.5f * Xin[(size_t)gi * 32 + gk] + 0.5f * R[gi] * sv;
    }
  }
}

// ---------------- phase: gram (bx<5, 5 j-partial pages) ---------------------
__device__ void gram_phase(const float* __restrict__ Xa, const float* __restrict__ Xb,
                           float* __restrict__ GPp, float* LDSu, int bx, int t) {
  float* sA = LDSu;
  float* sB = LDSu + 2048;
  float acc[4] = {0.f, 0.f, 0.f, 0.f};
  for (int c = 0; c < 5; ++c) {
    const int j0 = bx * 320 + c * 64;
    __syncthreads();
    for (int s = t; s < 2048; s += 256) {
      sA[s] = Xa[(size_t)j0 * 32 + s];
      sB[s] = Xb[(size_t)j0 * 32 + s];
    }
    __syncthreads();
#pragma unroll
    for (int s = 0; s < 4; ++s) {
      int e = s * 256 + t;
      int a = e >> 5, b = e & 31;
      float sum = 0.f;
#pragma unroll 8
      for (int jl = 0; jl < 64; ++jl) sum += sA[jl * 32 + a] * sB[jl * 32 + b];
      acc[s] += sum;
    }
  }
#pragma unroll
  for (int s = 0; s < 4; ++s)
    GPp[(size_t)bx * 1024 + s * 256 + t] = acc[s];
}

// ---------------- phase: apply (bx<200): chol + register trisolve -----------
__device__ void apply_phase(const float* __restrict__ GPp,
                            const float* __restrict__ Xin,
                            float* __restrict__ Xout, float* LDSu, int bx, int t) {
  float* Gm = LDSu;  // 32*33
#pragma unroll
  for (int u = 0; u < 4; ++u) {
    int e = t + u * 256;
    float g = 0.f;
#pragma unroll
    for (int p = 0; p < 5; ++p) g += GPp[p * 1024 + e];
    Gm[(e >> 5) * 33 + (e & 31)] = g;
  }
  const int r = t >> 5, l = t & 31;
  const int row = bx * 8 + r;
  float x = Xin[(size_t)row * M + l];
  __syncthreads();
  if (t < 64) {  // single-wave Cholesky, no barriers (wave-ordered LDS)
    for (int k = 0; k < 32; ++k) {
      if (t == k) Gm[k * 33 + k] = sqrtf(fmaxf(Gm[k * 33 + k], 1e-30f));
      float piv = Gm[k * 33 + k];
      if (t > k && t < 32) Gm[t * 33 + k] /= piv;
#pragma unroll
      for (int u = 0; u < 16; ++u) {
        int e = t + u * 64;
        int i = e >> 5, j = e & 31;
        if (i > k && j > k && j <= i)
          Gm[i * 33 + j] -= Gm[i * 33 + k] * Gm[j * 33 + k];
      }
    }
  }
  __syncthreads();
  const int half = t & 32;
  float y = 0.f;
  for (int k = 0; k < 32; ++k) {
    float gkl = Gm[k * 33 + l];
    float contrib = (l < k) ? y * gkl : 0.f;
#pragma unroll
    for (int o = 16; o; o >>= 1) contrib += __shfl_xor(contrib, o, 64);
    float xk = __shfl(x, half + k, 64);
    float yk = (xk - contrib) / Gm[k * 33 + k];
    if (l == k) y = yk;
  }
  Xout[(size_t)row * M + l] = y;
}

// ---------------- phase: rr (bx==0; all 256 threads at barriers) ------------
__device__ void rr_phase(const float* __restrict__ GPp,
                         const int* __restrict__ flags,
                         const int* __restrict__ Kptr,
                         float* __restrict__ out, float* LDSu, int t) {
  float* Bs   = LDSu;         // 1056
  float* part = LDSu + 1056;  // 1024
  float* evs  = LDSu + 2080;  // 32
  if (t < 64) {
#pragma unroll
    for (int u = 0; u < 16; ++u) {
      int e = t + u * 64;
      float g = 0.f;
#pragma unroll
      for (int p = 0; p < 5; ++p) g += GPp[p * 1024 + e];
      part[e] = g;
    }
  }
  __syncthreads();
  if (t < 64) {
#pragma unroll
    for (int u = 0; u < 16; ++u) {
      int e = t + u * 64;
      int i = e >> 5, j = e & 31;
      Bs[i * 33 + j] = 0.5f * (part[e] + part[j * 32 + i]);
    }
  }
  __syncthreads();
  if (t < 64) {
    const int tr = t & 31;
    float row[32];
#pragma unroll
    for (int c = 0; c < 32; ++c) row[c] = Bs[tr * 33 + c];
    float eer[32];
#pragma unroll
    for (int k = 0; k <= 29; ++k) {
      float xi = (t > k && t < 32) ? row[k] : 0.f;
      float nx2 = wred(xi * xi);
      float x0 = __shfl(xi, k + 1, 64);
      if (nx2 < 1e-28f) { eer[k] = x0; continue; }
      float alpha = (x0 >= 0.f) ? -sqrtf(nx2) : sqrtf(nx2);
      float h = nx2 - alpha * x0;
      float vv = (t == k + 1) ? (xi - alpha) : xi;
      eer[k] = alpha;
      float p0 = 0.f, p1 = 0.f, p2 = 0.f, p3 = 0.f;
#pragma unroll
      for (int c = 0; c < 32; c += 4) {
        p0 += row[c + 0] * __shfl(vv, c + 0, 64);
        p1 += row[c + 1] * __shfl(vv, c + 1, 64);
        p2 += row[c + 2] * __shfl(vv, c + 2, 64);
        p3 += row[c + 3] * __shfl(vv, c + 3, 64);
      }
      float pi = ((p0 + p1) + (p2 + p3)) / h;
      float vp = wred(vv * pi);
      float Kc = vp / (2.f * h);
      float uu = (t > k && t < 32) ? (pi - Kc * vv) : 0.f;
#pragma unroll
      for (int c = 0; c < 32; ++c) {
        float uc = __shfl(uu, c, 64);
        float vc = __shfl(vv, c, 64);
        row[c] -= vv * uc + uu * vc;
      }
    }
    float ddr[32];
#pragma unroll
    for (int c = 0; c < 32; ++c) ddr[c] = __shfl(row[c], c, 64);
    eer[30] = __shfl(row[30], 31, 64);
    eer[31] = 0.f;
    float ee2r[31];
#pragma unroll
    for (int c = 0; c < 31; ++c) ee2r[c] = eer[c] * eer[c];
    float lo = 1e30f, hi = -1e30f;
#pragma unroll
    for (int i = 0; i < 32; ++i) {
      float r = ((i > 0) ? fabsf(eer[i - 1]) : 0.f) +
                ((i < 31) ? fabsf(eer[i]) : 0.f);
      lo = fminf(lo, ddr[i] - r);
      hi = fmaxf(hi, ddr[i] + r);
    }
    lo -= 1e-6f; hi += 1e-6f;
    if (t < 32) {
      float a = lo, b = hi;
      for (int it = 0; it < BIS_IT; ++it) {
        float mid = 0.5f * (a + b);
        float q = ddr[0] - mid;
        int cnt = (q < 0.f) ? 1 : 0;
#pragma unroll
        for (int i = 1; i < 32; ++i) {
          float den = q;
          float ad = fabsf(den);
          den = (ad < 1e-30f) ? ((den < 0.f) ? -1e-30f : 1e-30f) : den;
          q = ddr[i] - mid - ee2r[i - 1] * __builtin_amdgcn_rcpf(den);
          cnt += (q < 0.f) ? 1 : 0;
        }
        if (cnt <= t) a = mid; else b = mid;
      }
      evs[t] = 0.5f * (a + b);
    }
  }
  __syncthreads();
  if (t == 0) {
    int K = Kptr ? *Kptr : 10;
    if (K < 1) K = 10;
    if (K > 32) K = 32;
    float t12 = 0.f, t13 = 0.f, t23 = 0.f;
    for (int b = 0; b < 8; ++b) {
      float f1 = flags[b * 2 + 0] ? 1.f : 0.f;
      float f2 = flags[b * 2 + 1] ? 1.f : 0.f;
      for (int k = 0; k < K; ++k) {
        float v1 = (k == 0) ? 0.f : (k == 1 ? f1 : 1.f);
        float v2 = (k == 0) ? 0.f : (k == 1 ? f2 : 1.f);
        float m3 = 2.f - 2.f * evs[31 - k];
        t12 += (v1 - v2) * (v1 - v2);
        t13 += (v1 - m3) * (v1 - m3);
        t23 += (v2 - m3) * (v2 - m3);
      }
    }
    out[0] = 5.f * (t12 + t13 + t23) / (8.f * (float)K);
  }
}

// ---------------- unified step dispatcher -----------------------------------
// Write-once X buffers: X(0)=degree; X(1..10)=mv; X(11)=apply1; X(12..21)=mv;
// X(22)=apply2; X(23)=mv21. GP aliases the dead RZ region — safe because the
// barrier's acquire fence invalidates stale lines.
__device__ void do_step(int s, const float* feats, float* RZ, float* F,
                        float* G4f, float* R, int* flags, float* GP, float* XB,
                        const int* Kptr, float* out, float* LDSu, int bx, int t) {
  const float4* G4 = (const float4*)G4f;
  float* GP1 = GP;
  float* GP2 = GP + 5120;
  float* GP3 = GP + 10240;
#define XBUF(i) (XB + (size_t)(i) * XSZ)
  if (s == 0) { if (bx < 168) resize_phase(feats, RZ, bx, t); return; }
  if (s == 1) { prep_phase(RZ, F, flags, LDSu, bx, t); return; }
  if (s == 2) { if (bx < 100) degree_phase(F, R, G4f, XBUF(0), LDSu, bx, t); return; }
  if (s >= 3 && s <= 12) {
    int m = s - 2;
    mv_phase(F, G4, R, XBUF(m - 1), XBUF(m), LDSu, bx, t);
    return;
  }
  if (s == 13) { if (bx < 5) gram_phase(XBUF(10), XBUF(10), GP1, LDSu, bx, t); return; }
  if (s == 14) { if (bx < 200) apply_phase(GP1, XBUF(10), XBUF(11), LDSu, bx, t); return; }
  if (s >= 15 && s <= 24) {
    int m = s - 3;  // 12..21
    mv_phase(F, G4, R, XBUF(m - 1), XBUF(m), LDSu, bx, t);
    return;
  }
  if (s == 25) { if (bx < 5) gram_phase(XBUF(21), XBUF(21), GP2, LDSu, bx, t); return; }
  if (s == 26) { if (bx < 200) apply_phase(GP2, XBUF(21), XBUF(22), LDSu, bx, t); return; }
  if (s == 27) { mv_phase(F, G4, R, XBUF(22), XBUF(23), LDSu, bx, t); return; }
  if (s == 28) { if (bx < 5) gram_phase(XBUF(22), XBUF(23), GP3, LDSu, bx, t); return; }
  if (s == 29) { if (bx == 0) rr_phase(GP3, flags, Kptr, out, LDSu, t); return; }
#undef XBUF
}

__global__ void __launch_bounds__(256)
k_solve(const float* feats, float* RZ, float* F, float* G4f, float* R,
        int* flags, float* GP, float* XB, const int* Kptr, float* out,
        unsigned* barr) {
  __shared__ __align__(16) float LDSu[LDSF];
  const int bx = blockIdx.x, t = threadIdx.x;
  for (int s = 0; s < NPH; ++s) {
    do_step(s, feats, RZ, F, G4f, R, flags, GP, XB, Kptr, out, LDSu, bx, t);
    if (s + 1 < NPH) grid_barrier(barr, s, bx, t);
  }
}

__global__ void __launch_bounds__(256)
k_step(int s, const float* feats, float* RZ, float* F, float* G4f, float* R,
       int* flags, float* GP, float* XB, const int* Kptr, float* out) {
  __shared__ __align__(16) float LDSu[LDSF];
  do_step(s, feats, RZ, F, G4f, R, flags, GP, XB, Kptr, out, LDSu,
          blockIdx.x, threadIdx.x);
}

// ---------------- host ------------------------------------------------------
extern "C" void kernel_launch(void* const* d_in, const int* in_sizes, int n_in,
                              void* d_out, int out_size, void* d_ws, size_t ws_size,
                              hipStream_t stream) {
  const float* feats = (const float*)d_in[0];
  const int* Kptr = (n_in > 1) ? (const int*)d_in[1] : nullptr;
  float* ws = (float*)d_ws;
  float* RZ = ws;                        // 38400 (dead after s=1; GP reuses it)
  float* GP = ws;                        // 3 x 5120 = 15360 <= 38400
  float* F  = ws + 38400;                // 4800
  float* G4f = ws + 43200;               // 6400 (1600 float4)
  float* R  = ws + 49600;                // 1600
  int* FLAGS = (int*)(ws + 51200);       // 16 ints (64 reserved)
  unsigned* BARR = (unsigned*)(ws + 51264);  // 18*1024 uints
  float* XB = ws + 51264 + 18 * 1024;    // 24 x XSZ write-once buffers
  // total = 69696 + 24*51200 = 1298496 floats ~= 5.19 MB
  float* outp = (float*)d_out;
  const float* fc = feats;

  hipMemsetAsync(BARR, 0, 18 * 1024 * 4, stream);  // barrier counters

  void* args[] = {(void*)&fc, (void*)&RZ, (void*)&F, (void*)&G4f, (void*)&R,
                  (void*)&FLAGS, (void*)&GP, (void*)&XB, (void*)&Kptr,
                  (void*)&outp, (void*)&BARR};
  hipError_t err = hipLaunchCooperativeKernel(
      (const void*)k_solve, dim3(NBLK, 1, 1), dim3(256, 1, 1), args, 0, stream);
  if (err != hipSuccess) {
    for (int s = 0; s < NPH; ++s)
      k_step<<<dim3(NBLK), dim3(256), 0, stream>>>(s, fc, RZ, F, G4f, R, FLAGS,
                                                   GP, XB, Kptr, outp);
  }
}

// Round 16
// 501.953 us; speedup vs baseline: 4.1240x; 4.1240x over previous
//
#include <hip/hip_runtime.h>
#include <math.h>

#define N16 1600
#define M 32
#define XSZ 51200
#define BIS_IT 28
#define EPSF 1e-12f

// FINAL CONFIGURATION — round-8/11 verified optimum (502.8 / 505.6 us).
// Session ledger of refuted alternatives:
//  - MV: blocks 200/400/500, chunk 64/320, barriers 26/6/2, LDS vs
//    direct-global XT — all ~15us/MV (residual = per-dispatch fixed cost).
//  - rr: ~70us floor across 7 implementations (LDS-batched, register/shfl);
//    additions regress via spill (+177us) or load-chain exposure (+50us).
//  - gram: 25 pages poisons single-wave consumers; 32-block G-row variant
//    latency-exposed (+40us); keep 5 pages.
//  - FUSION (round 15): cooperative 30-phase kernel passes but costs 2070us —
//    the per-barrier __threadfence L2 flush/invalidate re-streams 1.8 GB from
//    HBM (= measured 890 GB/s x 2ms). Kernel-boundary coherence (~8us x 29)
//    is strictly cheaper than any in-kernel coherence on 8 non-coherent XCDs.

// ---------------- phase: resize (168 blocks) --------------------------------
__device__ void taps1d(int o, int* lo, int* hi, float* wsum, float w[8]) {
  int l = 4 * o - 2, h = 4 * o + 5;
  if (l < 0) l = 0;
  if (h > 159) h = 159;
  float c = 4.f * o + 1.5f, s = 0.f;
  for (int x = l; x <= h; ++x) {
    float ww = 1.f - fabsf((float)x - c) * 0.25f;
    w[x - l] = ww;
    s += ww;
  }
  *lo = l; *hi = h; *wsum = s;
}

__global__ void __launch_bounds__(256)
k_resize(const float* __restrict__ in, float* __restrict__ rz) {
  const int bx = blockIdx.x, t = threadIdx.x;
  int map = bx / 7;
  int o = (bx % 7) * 256 + t;
  if (o >= N16) return;
  int oy = o / 40, ox = o % 40;
  int ly, hy, lx, hx; float sy, sx; float wy[8], wx[8];
  taps1d(oy, &ly, &hy, &sy, wy);
  taps1d(ox, &lx, &hx, &sx, wx);
  const float* src = in + (size_t)map * 160 * 160;
  float acc = 0.f;
  for (int y = ly; y <= hy; ++y) {
    float a = 0.f;
    const float* row = src + y * 160;
    for (int x = lx; x <= hx; ++x) a += wx[x - lx] * row[x];
    acc += wy[y - ly] * a;
  }
  rz[map * N16 + o] = acc / (sy * sx);
}

// ---------------- phase: prep (23 blocks) -----------------------------------
__global__ void __launch_bounds__(256)
k_prep(const float* __restrict__ rz, float* __restrict__ F,
       int* __restrict__ flags) {
  __shared__ int sp[256];
  __shared__ int sn[256];
  const int bx = blockIdx.x, t = threadIdx.x;
  if (bx < 16) {
    int b = bx >> 1, c = bx & 1;
    const float* m = rz + (b * 3 + c) * N16;
    int cp = 0, cn = 0;
    for (int o = t; o < N16; o += 256) {
      float v = m[o];
      cp += (v > 0.f);
      cn += (v < 0.f);
    }
    sp[t] = cp; sn[t] = cn;
    __syncthreads();
    for (int s = 128; s > 0; s >>= 1) {
      if (t < s) { sp[t] += sp[t + s]; sn[t] += sn[t + s]; }
      __syncthreads();
    }
    if (t == 0) flags[bx] = (sp[0] == 0 || sn[0] == 0) ? 1 : 0;
  } else {
    int n = (bx - 16) * 256 + t;
    if (n < N16) {
      float x = rz[n], y = rz[N16 + n], z = rz[2 * N16 + n];
      float nrm = sqrtf(x * x + y * y + z * z);
      float s = 1.f / fmaxf(nrm, EPSF);
      F[n * 3 + 0] = x * s;
      F[n * 3 + 1] = y * s;
      F[n * 3 + 2] = z * s;
    }
  }
}

// ---------------- phase: degree + G4 + X0 init (100 blocks) -----------------
__global__ void __launch_bounds__(256)
k_degree(const float* __restrict__ F, float* __restrict__ R,
         float* __restrict__ G4f, float* __restrict__ X0) {
  __shared__ float Fl[4800];
  __shared__ float red[256];
  const int bx = blockIdx.x, t = threadIdx.x;
  for (int s = t; s < 4800; s += 256) Fl[s] = F[s];
  __syncthreads();
  int rl = t >> 4, jt = t & 15;
  int i = bx * 16 + rl;
  float fx = Fl[i * 3], fy = Fl[i * 3 + 1], fz = Fl[i * 3 + 2];
  float s = 0.f;
#pragma unroll 8
  for (int j = jt; j < N16; j += 16) {
    float w = fx * Fl[j * 3] + fy * Fl[j * 3 + 1] + fz * Fl[j * 3 + 2];
    if (w > 0.f) s += w;
  }
  red[t] = s;
  __syncthreads();
  for (int st = 8; st > 0; st >>= 1) {
    if (jt < st) red[t] += red[t + st];
    __syncthreads();
  }
  if (jt == 0) {
    float d = red[t];
    if (d < EPSF) d = 1.f;
    float r = rsqrtf(d);
    R[i] = r;
    G4f[i * 4 + 0] = r * fx;
    G4f[i * 4 + 1] = r * fy;
    G4f[i * 4 + 2] = r * fz;
    G4f[i * 4 + 3] = 0.f;
  }
  for (int e = t; e < 512; e += 256) {
    int n = bx * 16 + (e >> 5);
    int k = e & 31;
    unsigned u = ((unsigned)n * 2654435761u) ^ ((unsigned)k * 0x9E3779B9u);
    u = u * 1664525u + 1013904223u;
    u ^= u >> 16; u *= 2246822519u; u ^= u >> 13;
    X0[n * M + k] = ((float)(u >> 8) * (1.f / 8388608.f)) - 1.f;
  }
}

// ---------------- phase: MV (400 blocks = 200 i-groups x 2 k-halves) --------
__global__ void __launch_bounds__(256)
k_mv(const float* __restrict__ F, const float4* __restrict__ G4,
     const float* __restrict__ R, const float* __restrict__ Xin,
     float* __restrict__ Xout) {
  __shared__ float Ws[2][8 * 324];    // [8 i][324] per buffer (320 j + pad)
  __shared__ float XsT[2][16 * 324];  // [16 k][324] per buffer (transposed X)
  __shared__ float Red[16 * 136];     // 16 jg pages x (8 i x 16 k), padded
  const int bx = blockIdx.x, t = threadIdx.x;
  const int ig = bx >> 1, kh = bx & 1;
  const int i0 = ig * 8, kbase = kh * 16;
  const int rg = t & 3, kg = (t >> 2) & 3, jg = t >> 4;  // compute: 4x4x16
  const int sj = t >> 2, sq = t & 3;                     // X stage: 64 j x 4 q
  const int wil = t & 7, wjg = t >> 3;                   // W stage: 8 i x 32 j
  const float fx = F[(i0 + wil) * 3 + 0];
  const float fy = F[(i0 + wil) * 3 + 1];
  const float fz = F[(i0 + wil) * 3 + 2];
  const float4* Xin4 = (const float4*)Xin;

  float acc[2][4];
#pragma unroll
  for (int r = 0; r < 2; ++r)
#pragma unroll
    for (int kk = 0; kk < 4; ++kk) acc[r][kk] = 0.f;

  // prologue: stage chunk 0 (j = 0..319) into buffer 0
#pragma unroll
  for (int p = 0; p < 5; ++p) {
    float4 xs = Xin4[(size_t)(p * 64 + sj) * 8 + kh * 4 + sq];
    XsT[0][(sq * 4 + 0) * 324 + p * 64 + sj] = xs.x;
    XsT[0][(sq * 4 + 1) * 324 + p * 64 + sj] = xs.y;
    XsT[0][(sq * 4 + 2) * 324 + p * 64 + sj] = xs.z;
    XsT[0][(sq * 4 + 3) * 324 + p * 64 + sj] = xs.w;
  }
#pragma unroll
  for (int q = 0; q < 10; ++q) {
    float4 g = G4[wjg + 32 * q];
    Ws[0][wil * 324 + wjg + 32 * q] =
        fmaxf(fx * g.x + fy * g.y + fz * g.z, 0.f);
  }
  __syncthreads();

  for (int c = 0; c < 5; ++c) {
    const int cur = c & 1, nxt = cur ^ 1;
    float4 xsr[5];
    float4 gar[10];
    if (c < 4) {  // issue next-chunk loads early (hide under compute)
      const int jb = (c + 1) * 320;
#pragma unroll
      for (int p = 0; p < 5; ++p)
        xsr[p] = Xin4[(size_t)(jb + p * 64 + sj) * 8 + kh * 4 + sq];
#pragma unroll
      for (int q = 0; q < 10; ++q) gar[q] = G4[jb + wjg + 32 * q];
    }
    // compute chunk c from buf[cur]: 5 sub-steps of 64 j
#pragma unroll
    for (int ss = 0; ss < 5; ++ss) {
      const int jq = ss * 64 + jg * 4;
      float4 wv[2], xv[4];
#pragma unroll
      for (int r = 0; r < 2; ++r)
        wv[r] = *(const float4*)&Ws[cur][(rg * 2 + r) * 324 + jq];
#pragma unroll
      for (int kk = 0; kk < 4; ++kk)
        xv[kk] = *(const float4*)&XsT[cur][(kg * 4 + kk) * 324 + jq];
#pragma unroll
      for (int r = 0; r < 2; ++r)
#pragma unroll
        for (int kk = 0; kk < 4; ++kk)
          acc[r][kk] += wv[r].x * xv[kk].x + wv[r].y * xv[kk].y +
                        wv[r].z * xv[kk].z + wv[r].w * xv[kk].w;
    }
    if (c < 4) {  // write-late into buf[nxt]
#pragma unroll
      for (int p = 0; p < 5; ++p) {
        XsT[nxt][(sq * 4 + 0) * 324 + p * 64 + sj] = xsr[p].x;
        XsT[nxt][(sq * 4 + 1) * 324 + p * 64 + sj] = xsr[p].y;
        XsT[nxt][(sq * 4 + 2) * 324 + p * 64 + sj] = xsr[p].z;
        XsT[nxt][(sq * 4 + 3) * 324 + p * 64 + sj] = xsr[p].w;
      }
#pragma unroll
      for (int q = 0; q < 10; ++q)
        Ws[nxt][wil * 324 + wjg + 32 * q] =
            fmaxf(fx * gar[q].x + fy * gar[q].y + fz * gar[q].z, 0.f);
    }
    __syncthreads();
  }

  // epilogue: reduce 16 jg-pages, apply 0.5*x + 0.5*R*sv, plain store
#pragma unroll
  for (int r = 0; r < 2; ++r)
#pragma unroll
    for (int kk = 0; kk < 4; ++kk)
      Red[jg * 136 + (rg * 2 + r) * 16 + (kg * 4 + kk)] = acc[r][kk];
  __syncthreads();
  if (t < 128) {
    const int il = t >> 4, kl = t & 15;
    float sv = 0.f;
#pragma unroll
    for (int g = 0; g < 16; ++g) sv += Red[g * 136 + il * 16 + kl];
    const int gi = i0 + il, gk = kbase + kl;
    Xout[(size_t)gi * 32 + gk] =
        0.5f * Xin[(size_t)gi * 32 + gk] + 0.5f * R[gi] * sv;
  }
}

// ---------------- phase: gram (5 blocks, j-partials; consumers sum) ---------
__global__ void __launch_bounds__(256)
k_gram(const float* __restrict__ Xa, const float* __restrict__ Xb,
       float* __restrict__ GPp) {
  __shared__ float sA[2048];
  __shared__ float sB[2048];
  const int bx = blockIdx.x, t = threadIdx.x;
  float acc[4] = {0.f, 0.f, 0.f, 0.f};
  for (int c = 0; c < 5; ++c) {
    const int j0 = bx * 320 + c * 64;
    __syncthreads();
    for (int s = t; s < 2048; s += 256) {
      sA[s] = Xa[(size_t)j0 * 32 + s];
      sB[s] = Xb[(size_t)j0 * 32 + s];
    }
    __syncthreads();
#pragma unroll
    for (int s = 0; s < 4; ++s) {
      int e = s * 256 + t;
      int a = e >> 5, b = e & 31;
      float sum = 0.f;
#pragma unroll 8
      for (int jl = 0; jl < 64; ++jl) sum += sA[jl * 32 + a] * sB[jl * 32 + b];
      acc[s] += sum;
    }
  }
#pragma unroll
  for (int s = 0; s < 4; ++s) GPp[(size_t)bx * 1024 + s * 256 + t] = acc[s];
}

// ---------------- phase: apply (200 blocks): chol + register trisolve -------
__global__ void __launch_bounds__(256)
k_apply(const float* __restrict__ GPp, const float* __restrict__ Xin,
        float* __restrict__ Xout) {
  __shared__ float Gm[32 * 33];
  const int bx = blockIdx.x, t = threadIdx.x;
#pragma unroll
  for (int u = 0; u < 4; ++u) {
    int e = t + u * 256;
    float g = 0.f;
#pragma unroll
    for (int p = 0; p < 5; ++p) g += GPp[p * 1024 + e];
    Gm[(e >> 5) * 33 + (e & 31)] = g;
  }
  const int r = t >> 5, l = t & 31;
  const int row = bx * 8 + r;
  float x = Xin[(size_t)row * M + l];
  __syncthreads();
  if (t < 64) {  // single-wave Cholesky, no barriers (wave-ordered LDS)
    for (int k = 0; k < 32; ++k) {
      if (t == k) Gm[k * 33 + k] = sqrtf(fmaxf(Gm[k * 33 + k], 1e-30f));
      float piv = Gm[k * 33 + k];
      if (t > k && t < 32) Gm[t * 33 + k] /= piv;
#pragma unroll
      for (int u = 0; u < 16; ++u) {
        int e = t + u * 64;
        int i = e >> 5, j = e & 31;
        if (i > k && j > k && j <= i)
          Gm[i * 33 + j] -= Gm[i * 33 + k] * Gm[j * 33 + k];
      }
    }
  }
  __syncthreads();
  const int half = t & 32;
  float y = 0.f;
  for (int k = 0; k < 32; ++k) {
    float gkl = Gm[k * 33 + l];
    float contrib = (l < k) ? y * gkl : 0.f;
#pragma unroll
    for (int o = 16; o; o >>= 1) contrib += __shfl_xor(contrib, o, 64);
    float xk = __shfl(x, half + k, 64);
    float yk = (xk - contrib) / Gm[k * 33 + k];
    if (l == k) y = yk;
  }
  Xout[(size_t)row * M + l] = y;
}

// ---------------- wave reductions (rr) --------------------------------------
__device__ __forceinline__ float wred(float v) {
#pragma unroll
  for (int o = 32; o; o >>= 1) v += __shfl_xor(v, o, 64);
  return v;
}

// ---------------- phase: rr (1 block x 1 wave, register-resident) -----------
__global__ void __launch_bounds__(64)
k_rr(const float* __restrict__ GPp, const int* __restrict__ flags,
     const int* __restrict__ Kptr, float* __restrict__ out) {
  __shared__ float Bs[1056];
  __shared__ float part[1024];
  __shared__ float evs[32];
  const int t = threadIdx.x;  // 0..63
#pragma unroll
  for (int u = 0; u < 16; ++u) {
    int e = t + u * 64;
    float g = 0.f;
#pragma unroll
    for (int p = 0; p < 5; ++p) g += GPp[p * 1024 + e];
    part[e] = g;
  }
  __syncthreads();
#pragma unroll
  for (int u = 0; u < 16; ++u) {
    int e = t + u * 64;
    int i = e >> 5, j = e & 31;
    Bs[i * 33 + j] = 0.5f * (part[e] + part[j * 32 + i]);
  }
  __syncthreads();
  const int tr = t & 31;
  float row[32];
#pragma unroll
  for (int c = 0; c < 32; ++c) row[c] = Bs[tr * 33 + c];
  float eer[32];
#pragma unroll
  for (int k = 0; k <= 29; ++k) {
    float xi = (t > k && t < 32) ? row[k] : 0.f;  // column k == row k (symm)
    float nx2 = wred(xi * xi);
    float x0 = __shfl(xi, k + 1, 64);
    if (nx2 < 1e-28f) { eer[k] = x0; continue; }
    float alpha = (x0 >= 0.f) ? -sqrtf(nx2) : sqrtf(nx2);
    float h = nx2 - alpha * x0;
    float vv = (t == k + 1) ? (xi - alpha) : xi;  // 0 outside active lanes
    eer[k] = alpha;
    float p0 = 0.f, p1 = 0.f, p2 = 0.f, p3 = 0.f;
#pragma unroll
    for (int c = 0; c < 32; c += 4) {
      p0 += row[c + 0] * __shfl(vv, c + 0, 64);
      p1 += row[c + 1] * __shfl(vv, c + 1, 64);
      p2 += row[c + 2] * __shfl(vv, c + 2, 64);
      p3 += row[c + 3] * __shfl(vv, c + 3, 64);
    }
    float pi = ((p0 + p1) + (p2 + p3)) / h;
    float vp = wred(vv * pi);  // vv==0 on inactive lanes -> exact 0 terms
    float Kc = vp / (2.f * h);
    float uu = (t > k && t < 32) ? (pi - Kc * vv) : 0.f;
#pragma unroll
    for (int c = 0; c < 32; ++c) {
      float uc = __shfl(uu, c, 64);
      float vc = __shfl(vv, c, 64);
      row[c] -= vv * uc + uu * vc;
    }
  }
  // extract tridiagonal (uniform across lanes via shfl; all static indices)
  float ddr[32];
#pragma unroll
  for (int c = 0; c < 32; ++c) ddr[c] = __shfl(row[c], c, 64);
  eer[30] = __shfl(row[30], 31, 64);
  eer[31] = 0.f;
  float ee2r[31];
#pragma unroll
  for (int c = 0; c < 31; ++c) ee2r[c] = eer[c] * eer[c];
  float lo = 1e30f, hi = -1e30f;
#pragma unroll
  for (int i = 0; i < 32; ++i) {
    float r = ((i > 0) ? fabsf(eer[i - 1]) : 0.f) +
              ((i < 31) ? fabsf(eer[i]) : 0.f);
    lo = fminf(lo, ddr[i] - r);
    hi = fmaxf(hi, ddr[i] + r);
  }
  lo -= 1e-6f; hi += 1e-6f;
  if (t < 32) {
    float a = lo, b = hi;
    for (int it = 0; it < BIS_IT; ++it) {
      float mid = 0.5f * (a + b);
      float q = ddr[0] - mid;
      int cnt = (q < 0.f) ? 1 : 0;
#pragma unroll
      for (int i = 1; i < 32; ++i) {
        float den = q;
        float ad = fabsf(den);
        den = (ad < 1e-30f) ? ((den < 0.f) ? -1e-30f : 1e-30f) : den;
        q = ddr[i] - mid - ee2r[i - 1] * __builtin_amdgcn_rcpf(den);
        cnt += (q < 0.f) ? 1 : 0;
      }
      if (cnt <= t) a = mid; else b = mid;
    }
    evs[t] = 0.5f * (a + b);
  }
  __syncthreads();
  if (t == 0) {
    int K = Kptr ? *Kptr : 10;
    if (K < 1) K = 10;
    if (K > 32) K = 32;
    float t12 = 0.f, t13 = 0.f, t23 = 0.f;
    for (int b = 0; b < 8; ++b) {
      float f1 = flags[b * 2 + 0] ? 1.f : 0.f;
      float f2 = flags[b * 2 + 1] ? 1.f : 0.f;
      for (int k = 0; k < K; ++k) {
        float v1 = (k == 0) ? 0.f : (k == 1 ? f1 : 1.f);
        float v2 = (k == 0) ? 0.f : (k == 1 ? f2 : 1.f);
        float m3 = 2.f - 2.f * evs[31 - k];
        t12 += (v1 - v2) * (v1 - v2);
        t13 += (v1 - m3) * (v1 - m3);
        t23 += (v2 - m3) * (v2 - m3);
      }
    }
    out[0] = 5.f * (t12 + t13 + t23) / (8.f * (float)K);
  }
}

// ---------------- host: 30 sequential launches ------------------------------
extern "C" void kernel_launch(void* const* d_in, const int* in_sizes, int n_in,
                              void* d_out, int out_size, void* d_ws, size_t ws_size,
                              hipStream_t stream) {
  const float* feats = (const float*)d_in[0];
  const int* Kptr = (n_in > 1) ? (const int*)d_in[1] : nullptr;
  float* ws = (float*)d_ws;
  float* RZ = ws;                         // 38400
  float* F  = ws + 38400;                 // 4800
  float* G4f = ws + 43200;                // 6400 (1600 float4)
  float* R  = ws + 49600;                 // 1600
  int* FLAGS = (int*)(ws + 51200);        // 16 ints (64 reserved)
  float* GP = ws + 51264;                 // 3 x 5 x 1024 partials
  float* XB = ws + 51264 + 15360;         // 4 x XSZ ring
  float* bufs[4] = {XB, XB + XSZ, XB + 2 * XSZ, XB + 3 * XSZ};
  const float4* G4 = (const float4*)G4f;
  float* outp = (float*)d_out;

  k_resize<<<dim3(168), dim3(256), 0, stream>>>(feats, RZ);
  k_prep<<<dim3(23), dim3(256), 0, stream>>>(RZ, F, FLAGS);
  k_degree<<<dim3(100), dim3(256), 0, stream>>>(F, R, G4f, bufs[0]);

  const float* cur = bufs[0];
  for (int m = 1; m <= 10; ++m) {
    float* o = bufs[1 + m % 3];
    k_mv<<<dim3(400), dim3(256), 0, stream>>>(F, G4, R, cur, o);
    cur = o;
  }
  k_gram<<<dim3(5), dim3(256), 0, stream>>>(cur, cur, GP);
  k_apply<<<dim3(200), dim3(256), 0, stream>>>(GP, cur, bufs[0]);  // XV1
  cur = bufs[0];
  for (int m = 11; m <= 20; ++m) {
    float* o = bufs[1 + m % 3];
    k_mv<<<dim3(400), dim3(256), 0, stream>>>(F, G4, R, cur, o);
    cur = o;
  }
  k_gram<<<dim3(5), dim3(256), 0, stream>>>(cur, cur, GP + 5120);
  k_apply<<<dim3(200), dim3(256), 0, stream>>>(GP + 5120, cur, bufs[0]);  // XV2
  k_mv<<<dim3(400), dim3(256), 0, stream>>>(F, G4, R, bufs[0], bufs[1]);  // X21
  k_gram<<<dim3(5), dim3(256), 0, stream>>>(bufs[0], bufs[1], GP + 10240);
  k_rr<<<dim3(1), dim3(64), 0, stream>>>(GP + 10240, FLAGS, Kptr, outp);
}